// Round 3
// baseline (47.253 us; speedup 1.0000x reference)
//
#include <hip/hip_runtime.h>

#define BB 16384
#define CC 10
#define KK 20
#define DD 128

// fast, accurate-enough log sigmoid: logsig(x) = min(x,0) - log(1 + exp(-|x|))
__device__ __forceinline__ float lsg(float x) {
    return fminf(x, 0.0f) - __logf(1.0f + __expf(-fabsf(x)));
}

// butterfly add via ds_swizzle (xor pattern within 32-lane halves). MASK is ICE.
template <int MASK>
__device__ __forceinline__ float swz_add(float v) {
    int r = __builtin_amdgcn_ds_swizzle(__float_as_int(v), MASK);
    return v + __int_as_float(r);
}

__device__ __forceinline__ float dot4(float4 a, float4 b) {
    return a.x * b.x + a.y * b.y + a.z * b.z + a.w * b.w;
}

__global__ __launch_bounds__(256, 8) void w2v_loss_kernel(
    const int*   __restrict__ context,   // [B, C]
    const int*   __restrict__ target,    // [B]
    const int*   __restrict__ negs,      // [B, K]
    const float* __restrict__ embW,      // [V, D]
    const float* __restrict__ ctxW,      // [V, D]
    float*       __restrict__ block_part // [gridDim.x]
) {
    const int wave  = threadIdx.x >> 6;
    const int lane  = threadIdx.x & 63;
    const int group = lane >> 5;          // 2 groups of 32 lanes per wave
    const int gl    = lane & 31;          // lane owns one float4 (16 B) of the 512 B row

    // 8 b's per block: 4 waves x 2 groups
    const int b = blockIdx.x * 8 + wave * 2 + group;

    const float4* ctxW4 = reinterpret_cast<const float4*>(ctxW);
    const float4* embW4 = reinterpret_cast<const float4*>(embW);

    const int* cbase = context + b * CC;
    const int* nbase = negs    + b * KK;

    // ---- prefetch all context indices + target (break idx->gather chains) ----
    int cidx[CC];
    #pragma unroll
    for (int c = 0; c < CC; ++c) cidx[c] = cbase[c];
    const int tidx = target[b];

    // ---- context mean (acc = one float4 per lane) ----
    float4 acc = make_float4(0.f, 0.f, 0.f, 0.f);
    #pragma unroll
    for (int c = 0; c < CC; ++c) {
        const float4 v = ctxW4[(size_t)cidx[c] * (DD / 4) + gl];
        acc.x += v.x; acc.y += v.y; acc.z += v.z; acc.w += v.w;
    }
    const float inv = 1.0f / CC;
    acc.x *= inv; acc.y *= inv; acc.z *= inv; acc.w *= inv;

    // ---- target dot partial ----
    float pd = dot4(acc, embW4[(size_t)tidx * (DD / 4) + gl]);

    // ---- negative dot partials, 4 rows in flight per batch ----
    float nd[KK];
    #pragma unroll
    for (int k = 0; k < KK; k += 4) {
        const int i0 = nbase[k + 0], i1 = nbase[k + 1];
        const int i2 = nbase[k + 2], i3 = nbase[k + 3];
        const float4 v0 = ctxW4[(size_t)i0 * (DD / 4) + gl];
        const float4 v1 = ctxW4[(size_t)i1 * (DD / 4) + gl];
        const float4 v2 = ctxW4[(size_t)i2 * (DD / 4) + gl];
        const float4 v3 = ctxW4[(size_t)i3 * (DD / 4) + gl];
        nd[k + 0] = dot4(acc, v0);
        nd[k + 1] = dot4(acc, v1);
        nd[k + 2] = dot4(acc, v2);
        nd[k + 3] = dot4(acc, v3);
    }

    // ---- reduce over 32 lanes: xor 1,2,4,8,16 via ds_swizzle (21 values, ILP) ----
    pd = swz_add<0x041F>(pd);
    #pragma unroll
    for (int k = 0; k < KK; ++k) nd[k] = swz_add<0x041F>(nd[k]);
    pd = swz_add<0x081F>(pd);
    #pragma unroll
    for (int k = 0; k < KK; ++k) nd[k] = swz_add<0x081F>(nd[k]);
    pd = swz_add<0x101F>(pd);
    #pragma unroll
    for (int k = 0; k < KK; ++k) nd[k] = swz_add<0x101F>(nd[k]);
    pd = swz_add<0x201F>(pd);
    #pragma unroll
    for (int k = 0; k < KK; ++k) nd[k] = swz_add<0x201F>(nd[k]);
    pd = swz_add<0x401F>(pd);
    #pragma unroll
    for (int k = 0; k < KK; ++k) nd[k] = swz_add<0x401F>(nd[k]);

    // ---- per-b score ----
    float score = lsg(pd);
    #pragma unroll
    for (int k = 0; k < KK; ++k) score += lsg(-nd[k]);

    // ---- combine the 2 groups of this wave ----
    float s = score + __shfl_xor(score, 32, 64);

    __shared__ float sp[4];
    if (lane == 0) sp[wave] = s;
    __syncthreads();
    if (threadIdx.x == 0)
        block_part[blockIdx.x] = sp[0] + sp[1] + sp[2] + sp[3];
}

__global__ __launch_bounds__(256) void w2v_finish_kernel(
    const float* __restrict__ part, float* __restrict__ out, int n, float scale)
{
    __shared__ float sm[4];
    float s = 0.f;
    for (int i = threadIdx.x; i < n; i += 256) s += part[i];
    #pragma unroll
    for (int off = 32; off; off >>= 1) s += __shfl_xor(s, off, 64);
    const int wave = threadIdx.x >> 6;
    const int lane = threadIdx.x & 63;
    if (lane == 0) sm[wave] = s;
    __syncthreads();
    if (threadIdx.x == 0) out[0] = (sm[0] + sm[1] + sm[2] + sm[3]) * scale;
}

extern "C" void kernel_launch(void* const* d_in, const int* in_sizes, int n_in,
                              void* d_out, int out_size, void* d_ws, size_t ws_size,
                              hipStream_t stream) {
    const int*   context = (const int*)d_in[0];
    const int*   target  = (const int*)d_in[1];
    const int*   negs    = (const int*)d_in[2];
    const float* embW    = (const float*)d_in[3];
    const float* ctxW    = (const float*)d_in[4];
    float* out = (float*)d_out;

    float* block_part = (float*)d_ws;          // 2048 floats = 8 KB scratch
    const int nblocks = BB / 8;                // 2048 blocks x 8 b's

    w2v_loss_kernel<<<nblocks, 256, 0, stream>>>(context, target, negs, embW, ctxW, block_part);
    w2v_finish_kernel<<<1, 256, 0, stream>>>(block_part, out, nblocks, -1.0f / (float)BB);
}

// Round 4
// 42.861 us; speedup vs baseline: 1.1025x; 1.1025x over previous
//
#include <hip/hip_runtime.h>

#define BB 16384
#define CC 10
#define KK 20
#define DD 128

// fast, accurate-enough log sigmoid: logsig(x) = min(x,0) - log(1 + exp(-|x|))
__device__ __forceinline__ float lsg(float x) {
    return fminf(x, 0.0f) - __logf(1.0f + __expf(-fabsf(x)));
}

// butterfly add via ds_swizzle (xor pattern within 32-lane halves). MASK is ICE.
template <int MASK>
__device__ __forceinline__ float swz_add(float v) {
    int r = __builtin_amdgcn_ds_swizzle(__float_as_int(v), MASK);
    return v + __int_as_float(r);
}

__device__ __forceinline__ float dot4(float4 a, float4 b) {
    return a.x * b.x + a.y * b.y + a.z * b.z + a.w * b.w;
}

// 16 lanes per batch element, 4 b per wave, 16 b per block.
// __launch_bounds__(256,4): grid residency is at most 4 waves/SIMD anyway
// (4096 waves / 256 CU); cap VGPR at 128 so NO spills and deep gather MLP.
__global__ __launch_bounds__(256, 4) void w2v_loss_kernel(
    const int*   __restrict__ context,   // [B, C]
    const int*   __restrict__ target,    // [B]
    const int*   __restrict__ negs,      // [B, K]
    const float* __restrict__ embW,      // [V, D]
    const float* __restrict__ ctxW,      // [V, D]
    float*       __restrict__ block_part // [gridDim.x]
) {
    const int tid   = threadIdx.x;
    const int wave  = tid >> 6;
    const int lane  = tid & 63;
    const int group = lane >> 4;          // 4 groups of 16 lanes per wave
    const int gl    = lane & 15;
    const int bl    = wave * 4 + group;   // 0..15 local batch element
    const int b0    = blockIdx.x * 16;

    // ---- cooperative index staging: one coalesced burst, then gathers fly ----
    __shared__ int s_ctx[16 * CC];   // 160 ints
    __shared__ int s_tgt[16];
    __shared__ int s_neg[16 * KK];   // 320 ints
    __shared__ float sp[4];

    if (tid < 16 * CC) s_ctx[tid] = context[b0 * CC + tid];
    if (tid < 16)      s_tgt[tid] = target[b0 + tid];
    s_neg[tid] = negs[b0 * KK + tid];
    if (tid < 16 * KK - 256) s_neg[256 + tid] = negs[b0 * KK + 256 + tid];
    __syncthreads();

    const float4* ctxW4 = reinterpret_cast<const float4*>(ctxW);
    const float4* embW4 = reinterpret_cast<const float4*>(embW);

    // each lane owns dims [4*gl..4*gl+3] and [64+4*gl..64+4*gl+3]
    // 32-bit row offsets: 100000 * 32 < 2^31, saves 64-bit addr VALU
    // ---- context mean ----
    float4 accA = make_float4(0.f, 0.f, 0.f, 0.f);
    float4 accB = make_float4(0.f, 0.f, 0.f, 0.f);
    #pragma unroll
    for (int c = 0; c < CC; ++c) {
        const int row = s_ctx[bl * CC + c] * (DD / 4);
        const float4 vA = ctxW4[row + gl];
        const float4 vB = ctxW4[row + 16 + gl];
        accA.x += vA.x; accA.y += vA.y; accA.z += vA.z; accA.w += vA.w;
        accB.x += vB.x; accB.y += vB.y; accB.z += vB.z; accB.w += vB.w;
    }
    const float inv = 1.0f / CC;
    accA.x *= inv; accA.y *= inv; accA.z *= inv; accA.w *= inv;
    accB.x *= inv; accB.y *= inv; accB.z *= inv; accB.w *= inv;

    // ---- target dot partial ----
    const int trow = s_tgt[bl] * (DD / 4);
    float pd = dot4(accA, embW4[trow + gl]) + dot4(accB, embW4[trow + 16 + gl]);

    // ---- negative dot partials (fully unrolled; compiler batches in-flight) ----
    float nd[KK];
    #pragma unroll
    for (int k = 0; k < KK; ++k) {
        const int row = s_neg[bl * KK + k] * (DD / 4);
        const float4 vA = ctxW4[row + gl];
        const float4 vB = ctxW4[row + 16 + gl];
        nd[k] = dot4(accA, vA) + dot4(accB, vB);
    }

    // ---- reduce over the 16 lanes of the group: xor 1,2,4,8 via ds_swizzle ----
    pd = swz_add<0x041F>(pd);
    #pragma unroll
    for (int k = 0; k < KK; ++k) nd[k] = swz_add<0x041F>(nd[k]);
    pd = swz_add<0x081F>(pd);
    #pragma unroll
    for (int k = 0; k < KK; ++k) nd[k] = swz_add<0x081F>(nd[k]);
    pd = swz_add<0x101F>(pd);
    #pragma unroll
    for (int k = 0; k < KK; ++k) nd[k] = swz_add<0x101F>(nd[k]);
    pd = swz_add<0x201F>(pd);
    #pragma unroll
    for (int k = 0; k < KK; ++k) nd[k] = swz_add<0x201F>(nd[k]);

    // ---- per-b score (4 b's of this wave computed in parallel) ----
    float score = lsg(pd);
    #pragma unroll
    for (int k = 0; k < KK; ++k) score += lsg(-nd[k]);

    // ---- combine the 4 groups of this wave: xor16 (swizzle) + xor32 (shfl) ----
    float s = swz_add<0x401F>(score);
    s += __shfl_xor(s, 32, 64);

    if (lane == 0) sp[wave] = s;
    __syncthreads();
    if (tid == 0)
        block_part[blockIdx.x] = sp[0] + sp[1] + sp[2] + sp[3];
}

__global__ __launch_bounds__(256) void w2v_finish_kernel(
    const float* __restrict__ part, float* __restrict__ out, int n, float scale)
{
    __shared__ float sm[4];
    float s = 0.f;
    for (int i = threadIdx.x; i < n; i += 256) s += part[i];
    #pragma unroll
    for (int off = 32; off; off >>= 1) s += __shfl_xor(s, off, 64);
    const int wave = threadIdx.x >> 6;
    const int lane = threadIdx.x & 63;
    if (lane == 0) sm[wave] = s;
    __syncthreads();
    if (threadIdx.x == 0) out[0] = (sm[0] + sm[1] + sm[2] + sm[3]) * scale;
}

extern "C" void kernel_launch(void* const* d_in, const int* in_sizes, int n_in,
                              void* d_out, int out_size, void* d_ws, size_t ws_size,
                              hipStream_t stream) {
    const int*   context = (const int*)d_in[0];
    const int*   target  = (const int*)d_in[1];
    const int*   negs    = (const int*)d_in[2];
    const float* embW    = (const float*)d_in[3];
    const float* ctxW    = (const float*)d_in[4];
    float* out = (float*)d_out;

    float* block_part = (float*)d_ws;          // 1024 floats = 4 KB scratch
    const int nblocks = BB / 16;               // 1024 blocks x 16 b's

    w2v_loss_kernel<<<nblocks, 256, 0, stream>>>(context, target, negs, embW, ctxW, block_part);
    w2v_finish_kernel<<<1, 256, 0, stream>>>(block_part, out, nblocks, -1.0f / (float)BB);
}